// Round 1
// baseline (245.316 us; speedup 1.0000x reference)
//
#include <hip/hip_runtime.h>

// CML1D: 15-step coupled map lattice, fp32, rows=2048, L=16384.
// grid <- drive; repeat 15x:
//   m = R*g*(1-g)
//   g = (1-BETA)*((1-EPS)*m + EPS*(K0*m[i-1]+K1*m[i]+K2*m[i+1])) + BETA*d
// out = clip(g, 1e-4, 1-1e-4)
//
// Fused algebraically: g' = c0*m[i-1] + c1*m[i] + c2*m[i+1] + BETA*d
//   c0=(1-B)E*K0, c1=(1-B)(1-E)+(1-B)E*K1, c2=(1-B)E*K2
//
// One block per row. 1024 threads x 16 contiguous elements each, all state in
// registers. Only chunk-endpoint mapped values cross threads -> tiny LDS halo
// exchange, double-buffered so ONE barrier per step is race-free.

constexpr float Rc    = 3.9f;
constexpr float EPSc  = 0.3f;
constexpr float BETAc = 0.15f;
constexpr int   STEPS = 15;
constexpr int   L     = 16384;
constexpr int   T     = 1024;
constexpr int   C     = L / T;  // 16 elements per thread

__global__ __launch_bounds__(1024, 8)
void cml1d_kernel(const float* __restrict__ drive,
                  const float* __restrict__ K,
                  float* __restrict__ out) {
    // double-buffered halo exchange: [parity][thread]
    __shared__ float sm_first[2][T];  // m[0] of each thread's chunk
    __shared__ float sm_last[2][T];   // m[C-1] of each thread's chunk

    const int t = threadIdx.x;
    const size_t base = (size_t)blockIdx.x * L + (size_t)t * C;
    const float4* __restrict__ d4 = reinterpret_cast<const float4*>(drive + base);
    float4* __restrict__ o4 = reinterpret_cast<float4*>(out + base);

    const float K0 = K[0], K1 = K[1], K2 = K[2];
    const float A  = (1.0f - BETAc) * (1.0f - EPSc);   // 0.595
    const float B  = (1.0f - BETAc) * EPSc;            // 0.255
    const float c0 = B * K0;
    const float c1 = A + B * K1;
    const float c2 = B * K2;

    float d[C], g[C];
    #pragma unroll
    for (int j = 0; j < C / 4; ++j) {
        float4 v = d4[j];
        d[4*j+0] = v.x; d[4*j+1] = v.y; d[4*j+2] = v.z; d[4*j+3] = v.w;
    }
    #pragma unroll
    for (int i = 0; i < C; ++i) g[i] = d[i];

    const int tl = (t == 0)     ? (T - 1) : (t - 1);
    const int tr = (t == T - 1) ? 0       : (t + 1);

    for (int s = 0; s < STEPS; ++s) {
        const int pb = s & 1;
        // logistic map at the chunk endpoints, published for neighbor threads
        float t0 = Rc * g[0];
        float m0 = t0 - t0 * g[0];          // R*g*(1-g) as mul+fma
        float t1 = Rc * g[C-1];
        float mlast = t1 - t1 * g[C-1];
        sm_first[pb][t] = m0;
        sm_last[pb][t]  = mlast;
        __syncthreads();
        float mprev = sm_last[pb][tl];      // m[i-1] halo (circular)
        float mrh   = sm_first[pb][tr];     // m[i+1] halo (circular)

        // rolling 3-wide window: each m computed exactly once
        float mcur = m0;
        #pragma unroll
        for (int i = 0; i < C; ++i) {
            float mnext;
            if (i == C - 1)      mnext = mrh;
            else if (i == C - 2) mnext = mlast;
            else {
                float tt = Rc * g[i+1];
                mnext = tt - tt * g[i+1];
            }
            g[i] = c0 * mprev + (c1 * mcur + (c2 * mnext + BETAc * d[i]));
            mprev = mcur;
            mcur  = mnext;
        }
    }

    const float lo = (float)(0.0001);
    const float hi = (float)(1.0 - 0.0001);
    #pragma unroll
    for (int j = 0; j < C / 4; ++j) {
        float4 v;
        v.x = fminf(fmaxf(g[4*j+0], lo), hi);
        v.y = fminf(fmaxf(g[4*j+1], lo), hi);
        v.z = fminf(fmaxf(g[4*j+2], lo), hi);
        v.w = fminf(fmaxf(g[4*j+3], lo), hi);
        o4[j] = v;
    }
}

extern "C" void kernel_launch(void* const* d_in, const int* in_sizes, int n_in,
                              void* d_out, int out_size, void* d_ws, size_t ws_size,
                              hipStream_t stream) {
    const float* drive = (const float*)d_in[0];
    const float* K     = (const float*)d_in[1];
    float* out         = (float*)d_out;
    const int rows = in_sizes[0] / L;  // 2048
    cml1d_kernel<<<dim3(rows), dim3(T), 0, stream>>>(drive, K, out);
}